// Round 12
// baseline (263.500 us; speedup 1.0000x reference)
//
#include <hip/hip_runtime.h>
#include <hip/hip_bf16.h>
#include <stdint.h>

#define NN 50000
#define NE 1600000
#define CIN 512
#define CH1 256
#define CH2 32

#define NBUCK 196          // ceil(50000/256) buckets of 256 nodes
#define CAP 10240          // per-bucket raw edge capacity (avg 8163, +23 sigma)
#define CAP2 16384         // padded capacity: CAP + 256*16 pad/self <= 14336
#define ECH 4096           // edges per binning block
#define NCH 391            // ceil(NE/ECH)

// node split: [0,NS) -> L3 contiguous-row path, [NS,NN) -> L2 plane path
#define NS  14016          // multiple of 64 and 16
#define NBP ((NN - NS + 63) / 64)   // 563 plane-block groups (x8 slices)
#define NBC (NS / 16)               // 876 L3-path blocks

typedef __bf16 bf16_t;
typedef __attribute__((ext_vector_type(2))) __bf16 bf16x2;
typedef __attribute__((ext_vector_type(8))) __bf16 bf16x8;
typedef __attribute__((ext_vector_type(4))) float f32x4;
typedef __attribute__((ext_vector_type(2))) float f32x2;
typedef __attribute__((ext_vector_type(4))) uint32_t u32x4;

__device__ inline float blo(uint32_t v) { return __uint_as_float(v << 16); }
__device__ inline float bhi(uint32_t v) { return __uint_as_float(v & 0xffff0000u); }
__device__ inline uint32_t pk2(float a, float b) {
  bf16x2 p; p[0] = (__bf16)a; p[1] = (__bf16)b; return *(uint32_t*)&p;
}
#define RACC(v, A0, A1, A2, A3) { \
    f32x2 t0 = {blo(v.x), bhi(v.x)}; A0 += t0; \
    f32x2 t1 = {blo(v.y), bhi(v.y)}; A1 += t1; \
    f32x2 t2 = {blo(v.z), bhi(v.z)}; A2 += t2; \
    f32x2 t3 = {blo(v.w), bhi(v.w)}; A3 += t3; }

// ============ CSR build: bucketed counting sort, no global atomics ============
__global__ __launch_bounds__(256) void k_hist(const int* __restrict__ dst,
                                              int* __restrict__ counts) {
  __shared__ int h[256];
  int blk = blockIdx.x, t = threadIdx.x;
  int e0 = blk * ECH;
  int ce = NE - e0; if (ce > ECH) ce = ECH;
  h[t] = 0;
  __syncthreads();
  for (int k = t; k < ce; k += 256) atomicAdd(&h[dst[e0 + k] >> 8], 1);
  __syncthreads();
  if (t < NBUCK) counts[blk * NBUCK + t] = h[t];
}

__global__ __launch_bounds__(512) void k_scanb(const int* __restrict__ counts,
                                               int* __restrict__ offs,
                                               int* __restrict__ bcnt) {
  __shared__ int l[512];
  int b = blockIdx.x, t = threadIdx.x;
  int v = (t < NCH) ? counts[t * NBUCK + b] : 0;
  int x = v;
  l[t] = x;
  __syncthreads();
  for (int off = 1; off < 512; off <<= 1) {
    int u = (t >= off) ? l[t - off] : 0;
    __syncthreads();
    x += u; l[t] = x;
    __syncthreads();
  }
  if (t < NCH) offs[t * NBUCK + b] = b * CAP + (x - v);
  if (t == 511) bcnt[b] = x;
}

// P1c: single-pass direct scatter into block-private regions.
__global__ __launch_bounds__(256) void k_bin(const int* __restrict__ src,
    const int* __restrict__ dst, const int* __restrict__ offs,
    uint32_t* __restrict__ binned) {
  __shared__ int lcnt[256], offsL[256];
  int blk = blockIdx.x, t = threadIdx.x;
  int e0 = blk * ECH;
  int ce = NE - e0; if (ce > ECH) ce = ECH;
  lcnt[t] = 0;
  if (t < NBUCK) offsL[t] = offs[blk * NBUCK + t];
  __syncthreads();
  for (int k = t; k < ce; k += 256) {
    int d = dst[e0 + k], s = src[e0 + k];
    int bkt = d >> 8;
    int p = atomicAdd(&lcnt[bkt], 1);
    binned[offsL[bkt] + p] = ((uint32_t)(d & 255) << 16) | (uint32_t)s;
  }
}

// P2: one block per bucket -> padded u16 src lists with self-loops + sentinels.
// Sentinel src == NN points at the zero row.
__global__ __launch_bounds__(256) void k_build(const uint32_t* __restrict__ binned,
    const int* __restrict__ bcnt, int* __restrict__ rowptr2, int* __restrict__ deg2,
    float* __restrict__ dinv, uint16_t* __restrict__ csrs) {
  __shared__ int hist[256], prow[256], lcnt[256];
  __shared__ int tot_s;
  __shared__ uint32_t c2[CAP2];
  int b = blockIdx.x, t = threadIdx.x;
  int count = bcnt[b];
  hist[t] = 0; lcnt[t] = 0;
  __syncthreads();
  const uint32_t* bb = binned + (size_t)b * CAP;
  for (int j = t; j < count; j += 256) atomicAdd(&hist[bb[j] >> 16], 1);
  __syncthreads();
  int node = b * 256 + t;
  int deg = hist[t];
  int pdeg = (node < NN) ? ((deg + 16) & ~15) : 0;   // deg + self, pad to 16
  int x = pdeg;
  prow[t] = x;
  __syncthreads();
  for (int off = 1; off < 256; off <<= 1) {
    int u = (t >= off) ? prow[t - off] : 0;
    __syncthreads();
    x += u; prow[t] = x;
    __syncthreads();
  }
  int start = x - pdeg;
  prow[t] = start;
  if (t == 255) tot_s = x;
  if (node < NN) {
    rowptr2[node] = b * CAP2 + start;
    deg2[node] = pdeg;
    dinv[node] = 1.0f / sqrtf((float)(deg + 1));     // deg incl. self-loop
    c2[start + deg] = (uint32_t)node;                // self
    for (int k = deg + 1; k < pdeg; ++k)
      c2[start + k] = (uint32_t)NN;                  // pad -> zero row
  }
  __syncthreads();
  for (int j = t; j < count; j += 256) {
    uint32_t e = bb[j];
    int dl = e >> 16;
    int p = prow[dl] + atomicAdd(&lcnt[dl], 1);
    c2[p] = e & 0xffffu;
  }
  __syncthreads();
  int tot = tot_s;
  uint16_t* co = csrs + (size_t)b * CAP2;
  for (int j = t; j < tot; j += 256) co[j] = (uint16_t)c2[j];
}

// ---------------- weight prep (transpose to bf16) + zero-row init ----------------
__global__ void k_prep_w(const float* __restrict__ W1, const float* __restrict__ W2,
                         bf16_t* __restrict__ w1t, bf16_t* __restrict__ w2t,
                         uint32_t* __restrict__ h1p_u32, uint32_t* __restrict__ h2b_u32,
                         uint32_t* __restrict__ h1c_u32) {
  int i = blockIdx.x * 256 + threadIdx.x;
  if (i < CIN * CH1) {
    int n = i >> 9, k = i & 511;
    w1t[i] = (__bf16)W1[k * CH1 + n];            // w1t[n][k]
  }
  if (i < CH1 * CH2) {
    int oc = i >> 8, k = i & 255;
    w2t[i] = (__bf16)W2[k * CH2 + oc];           // w2t[oc][k]
  }
  if (blockIdx.x == 0) {
    int t = threadIdx.x;
    if (t < 128) {                                // zero row NN of 8 h1 planes
      int p = t >> 4;
      h1p_u32[((size_t)p * (NN + 1) + NN) * 16 + (t & 15)] = 0;
    } else if (t < 144) {                         // zero row NN of h2b
      h2b_u32[(size_t)NN * 16 + (t - 128)] = 0;
    }
  } else if (blockIdx.x == 1) {
    int t = threadIdx.x;
    if (t < 128) h1c_u32[(size_t)NN * 128 + t] = 0;  // zero row NN of h1c
  }
}

// ---------------- GEMM1: h1 planes + h1c = bf16( dinv .* (x @ W1) ) ----------------
#define BM 64
#define BN 256
#define BK 64

__global__ __launch_bounds__(256) void k_gemm1(const float* __restrict__ X,
                                               const bf16_t* __restrict__ BT,
                                               const float* __restrict__ dinv,
                                               bf16_t* __restrict__ h1p,
                                               bf16_t* __restrict__ h1c) {
  __shared__ __align__(16) bf16_t ldsA[2][BM * BK];
  __shared__ __align__(16) bf16_t ldsB[2][BN * BK];
  const int tid = threadIdx.x;
  const int lane = tid & 63;
  const int wid = tid >> 6;          // waves tile the 256-col dim
  const int tm = blockIdx.x;

  f32x4 acc[4][4] = {};
  float4 ra[2], rb[2];

  auto loadA = [&](int kt) {
#pragma unroll
    for (int q = 0; q < 2; ++q) {
      int idx16 = q * 256 + tid;
      int r = idx16 >> 3, cw = idx16 & 7;
      int grow = tm * BM + r;
      grow = grow < NN ? grow : NN - 1;
      const float* ga = X + (size_t)grow * CIN + kt * BK + cw * 8;
      ra[q] = *(const float4*)ga;
      rb[q] = *(const float4*)(ga + 4);
    }
  };
  auto writeA = [&](int buf) {
#pragma unroll
    for (int q = 0; q < 2; ++q) {
      int idx16 = q * 256 + tid;
      int r = idx16 >> 3, cw = idx16 & 7;
      bf16x8 o;
      o[0] = (__bf16)ra[q].x; o[1] = (__bf16)ra[q].y;
      o[2] = (__bf16)ra[q].z; o[3] = (__bf16)ra[q].w;
      o[4] = (__bf16)rb[q].x; o[5] = (__bf16)rb[q].y;
      o[6] = (__bf16)rb[q].z; o[7] = (__bf16)rb[q].w;
      *(bf16x8*)&ldsA[buf][r * 64 + ((cw ^ (r & 7)) << 3)] = o;
    }
  };
  auto stageB = [&](int buf, int kt) {
#pragma unroll
    for (int t = 0; t < 8; ++t) {
      int o = t * 4096 + tid * 16;
      int r = o >> 7, cw = (o >> 4) & 7;
      int lc = cw ^ (r & 7);
      const bf16_t* gb = BT + (size_t)r * CIN + kt * BK + lc * 8;
      __builtin_amdgcn_global_load_lds(
          (const __attribute__((address_space(1))) void*)gb,
          (__attribute__((address_space(3))) void*)&ldsB[buf][(t * 4096 + wid * 1024) >> 1],
          16, 0, 0);
    }
  };

  loadA(0);
  stageB(0, 0);
  writeA(0);
  __syncthreads();
  int cur = 0;
  for (int kt = 0; kt < CIN / BK; ++kt) {
    if (kt + 1 < CIN / BK) { loadA(kt + 1); stageB(cur ^ 1, kt + 1); }
#pragma unroll
    for (int ks = 0; ks < 2; ++ks) {
      bf16x8 af[4], bfr[4];
#pragma unroll
      for (int m = 0; m < 4; ++m) {
        int row = m * 16 + (lane & 15);
        int kc = ks * 4 + (lane >> 4);
        af[m] = *(const bf16x8*)&ldsA[cur][row * 64 + ((kc ^ (row & 7)) << 3)];
      }
#pragma unroll
      for (int n = 0; n < 4; ++n) {
        int col = wid * 64 + n * 16 + (lane & 15);
        int kc = ks * 4 + (lane >> 4);
        bfr[n] = *(const bf16x8*)&ldsB[cur][col * 64 + ((kc ^ (col & 7)) << 3)];
      }
#pragma unroll
      for (int m = 0; m < 4; ++m)
#pragma unroll
        for (int n = 0; n < 4; ++n)
          acc[m][n] = __builtin_amdgcn_mfma_f32_16x16x32_bf16(af[m], bfr[n], acc[m][n], 0, 0, 0);
    }
    if (kt + 1 < CIN / BK) writeA(cur ^ 1);
    __syncthreads();
    cur ^= 1;
  }

#pragma unroll
  for (int m = 0; m < 4; ++m) {
#pragma unroll
    for (int r = 0; r < 4; ++r) {
      int grow = tm * BM + m * 16 + (lane >> 4) * 4 + r;
      if (grow < NN) {
        float dv = dinv[grow];
#pragma unroll
        for (int n = 0; n < 4; ++n) {
          int gcol = wid * 64 + n * 16 + (lane & 15);
          int plane = gcol >> 5, pc = gcol & 31;
          bf16_t val = (__bf16)(dv * acc[m][n][r]);
          h1p[(size_t)plane * ((NN + 1) * 32) + (size_t)grow * 32 + pc] = val;
          h1c[(size_t)grow * 256 + gcol] = val;   // contiguous copy for L3 path
        }
      }
    }
  }
}

// ---------------- agg1: dual-path gather ----------------
// Plane path (nodes >= NS): 16 nodes x 4 lanes, 64B rows from the XCD-pinned
// 3.2 MB plane (s = blockIdx&7). L3 path (nodes < NS): 4 nodes x 16 lanes,
// full 512B rows from the contiguous h1c copy, nontemporal (L3-served) so the
// planes stay resident. The two paths run concurrently on independent
// memory resources (per-XCD L2 random-touch rate vs Infinity Cache BW).
__global__ __launch_bounds__(256) void k_agg1(const uint32_t* __restrict__ h1p,
    const uint32_t* __restrict__ h1c,
    const int* __restrict__ rowptr2, const int* __restrict__ deg2,
    const uint16_t* __restrict__ csrs, const float* __restrict__ dinv,
    const float* __restrict__ bias, uint32_t* __restrict__ hrp) {
  const int lane = threadIdx.x & 63;
  const int wid = threadIdx.x >> 6;
  if (blockIdx.x < NBP * 8) {
    // ---- plane path ----
    const int s = blockIdx.x & 7;
    int i = NS + (blockIdx.x >> 3) * 64 + wid * 16 + (lane >> 2);
    const bool valid = i < NN;
    i = valid ? i : NN - 1;
    const int cl = lane & 3;
    const int grp = lane & 60;
    const int cb = cl << 4;
    const char* __restrict__ Pb = (const char*)(h1p + (size_t)s * ((NN + 1) * 16));

    f32x2 a0 = {0.f, 0.f}, a1 = {0.f, 0.f}, a2 = {0.f, 0.f}, a3 = {0.f, 0.f};
    const int base = rowptr2[i];
    const int pdeg = deg2[i];
    uint32_t ent = __builtin_nontemporal_load((const uint32_t*)&csrs[base + cl * 2]);
    for (int b0 = 0; b0 < pdeg; b0 += 8) {
      uint32_t ent_n = __builtin_nontemporal_load(
          (const uint32_t*)&csrs[base + b0 + 8 + cl * 2]);
      int s0 = (int)(ent & 0xffffu) << 6;
      int s1 = (int)(ent >> 16) << 6;
#pragma unroll
      for (int e = 0; e < 8; ++e) {
        int off = __shfl((e & 1) ? s1 : s0, grp + (e >> 1)) + cb;
        u32x4 v = *(const u32x4*)(Pb + off);
        RACC(v, a0, a1, a2, a3);
      }
      ent = ent_n;
    }
    float di = dinv[i];
    float4 b0v = *(const float4*)&bias[s * 32 + cl * 8];
    float4 b1v = *(const float4*)&bias[s * 32 + cl * 8 + 4];
    u32x4 o;
    o.x = pk2(fmaxf(di * a0.x + b0v.x, 0.f), fmaxf(di * a0.y + b0v.y, 0.f));
    o.y = pk2(fmaxf(di * a1.x + b0v.z, 0.f), fmaxf(di * a1.y + b0v.w, 0.f));
    o.z = pk2(fmaxf(di * a2.x + b1v.x, 0.f), fmaxf(di * a2.y + b1v.y, 0.f));
    o.w = pk2(fmaxf(di * a3.x + b1v.z, 0.f), fmaxf(di * a3.y + b1v.w, 0.f));
    if (valid)
      __builtin_nontemporal_store(o,
          (u32x4*)&hrp[((size_t)s * NN + i) * 16 + cl * 4]);
  } else {
    // ---- L3 path: full 512B rows from h1c ----
    const int bidx = blockIdx.x - NBP * 8;
    const int i = bidx * 16 + wid * 4 + (lane >> 4);   // always < NS
    const int cl = lane & 15;                          // owns ch [16cl,16cl+16)
    const int grp = lane & 48;
    const int cb = cl << 5;                            // 32B per lane
    const char* __restrict__ Pb = (const char*)h1c;

    f32x2 a0 = {0.f, 0.f}, a1 = {0.f, 0.f}, a2 = {0.f, 0.f}, a3 = {0.f, 0.f};
    f32x2 a4 = {0.f, 0.f}, a5 = {0.f, 0.f}, a6 = {0.f, 0.f}, a7 = {0.f, 0.f};
    const int base = rowptr2[i];
    const int pdeg = deg2[i];                          // multiple of 16
    int ent = (int)__builtin_nontemporal_load(&csrs[base + cl]);
    for (int b0 = 0; b0 < pdeg; b0 += 16) {
      int ent_n = (int)__builtin_nontemporal_load(&csrs[base + b0 + 16 + cl]);
      int sc = ent << 9;                               // 512B row stride
#pragma unroll
      for (int e = 0; e < 16; ++e) {
        int off = __shfl(sc, grp + e) + cb;
        u32x4 v = __builtin_nontemporal_load((const u32x4*)(Pb + off));
        u32x4 w = __builtin_nontemporal_load((const u32x4*)(Pb + off + 16));
        RACC(v, a0, a1, a2, a3);
        RACC(w, a4, a5, a6, a7);
      }
      ent = ent_n;
    }
    float di = dinv[i];
    float4 q0 = *(const float4*)&bias[cl * 16 + 0];
    float4 q1 = *(const float4*)&bias[cl * 16 + 4];
    float4 q2 = *(const float4*)&bias[cl * 16 + 8];
    float4 q3 = *(const float4*)&bias[cl * 16 + 12];
    u32x4 o0, o1;
    o0.x = pk2(fmaxf(di * a0.x + q0.x, 0.f), fmaxf(di * a0.y + q0.y, 0.f));
    o0.y = pk2(fmaxf(di * a1.x + q0.z, 0.f), fmaxf(di * a1.y + q0.w, 0.f));
    o0.z = pk2(fmaxf(di * a2.x + q1.x, 0.f), fmaxf(di * a2.y + q1.y, 0.f));
    o0.w = pk2(fmaxf(di * a3.x + q1.z, 0.f), fmaxf(di * a3.y + q1.w, 0.f));
    o1.x = pk2(fmaxf(di * a4.x + q2.x, 0.f), fmaxf(di * a4.y + q2.y, 0.f));
    o1.y = pk2(fmaxf(di * a5.x + q2.z, 0.f), fmaxf(di * a5.y + q2.w, 0.f));
    o1.z = pk2(fmaxf(di * a6.x + q3.x, 0.f), fmaxf(di * a6.y + q3.y, 0.f));
    o1.w = pk2(fmaxf(di * a7.x + q3.z, 0.f), fmaxf(di * a7.y + q3.w, 0.f));
    const int kb = cl >> 1;
    size_t idx = ((size_t)kb * NN + i) * 16 + (cl & 1) * 8;
    __builtin_nontemporal_store(o0, (u32x4*)&hrp[idx]);
    __builtin_nontemporal_store(o1, (u32x4*)&hrp[idx + 4]);
  }
}

// ---------------- GEMM2 (MFMA): h2b = bf16( dinv .* (hr @ W2) ) ----------------
__global__ __launch_bounds__(256) void k_gemm2(const bf16_t* __restrict__ hrp,
    const bf16_t* __restrict__ w2t, const float* __restrict__ dinv,
    bf16_t* __restrict__ h2b) {
  const int lane = threadIdx.x & 63;
  const int gw = blockIdx.x * 4 + (threadIdx.x >> 6);
  const int r0 = gw * 16;
  if (r0 >= NN) return;
  int arow = r0 + (lane & 15);
  arow = arow < NN ? arow : NN - 1;
  const int kc = lane >> 4;
  f32x4 acc0 = {}, acc1 = {};
#pragma unroll
  for (int kb = 0; kb < 8; ++kb) {
    bf16x8 a  = *(const bf16x8*)&hrp[(size_t)kb * (NN * 32) + (size_t)arow * 32 + kc * 8];
    bf16x8 b0 = *(const bf16x8*)&w2t[(size_t)(lane & 15) * CH1 + kb * 32 + kc * 8];
    bf16x8 b1 = *(const bf16x8*)&w2t[(size_t)(16 + (lane & 15)) * CH1 + kb * 32 + kc * 8];
    acc0 = __builtin_amdgcn_mfma_f32_16x16x32_bf16(a, b0, acc0, 0, 0, 0);
    acc1 = __builtin_amdgcn_mfma_f32_16x16x32_bf16(a, b1, acc1, 0, 0, 0);
  }
#pragma unroll
  for (int r = 0; r < 4; ++r) {
    int rr = r0 + (lane >> 4) * 4 + r;
    if (rr < NN) {
      float dv = dinv[rr];
      h2b[(size_t)rr * CH2 + (lane & 15)]      = (__bf16)(dv * acc0[r]);
      h2b[(size_t)rr * CH2 + 16 + (lane & 15)] = (__bf16)(dv * acc1[r]);
    }
  }
}

// ---------------- agg2 + bias + linear + log_softmax (16 nodes x 4 lanes) ----------------
__global__ __launch_bounds__(256) void k_agg2(const uint32_t* __restrict__ h2b,
    const int* __restrict__ rowptr2, const int* __restrict__ deg2,
    const uint16_t* __restrict__ csrs, const float* __restrict__ dinv,
    const float* __restrict__ b2, const float* __restrict__ Wl,
    const float* __restrict__ bl, float* __restrict__ out) {
  const int lane = threadIdx.x & 63;
  const int wid = threadIdx.x >> 6;
  int i = blockIdx.x * 64 + wid * 16 + (lane >> 2);
  const bool valid = i < NN;
  i = valid ? i : NN - 1;
  const int cl = lane & 3;
  const int grp = lane & 60;
  const int cb = cl << 4;
  const char* __restrict__ Pb = (const char*)h2b;

  f32x2 a0 = {0.f, 0.f}, a1 = {0.f, 0.f}, a2 = {0.f, 0.f}, a3 = {0.f, 0.f};
  const int base = rowptr2[i];
  const int pdeg = deg2[i];
  uint32_t ent = __builtin_nontemporal_load((const uint32_t*)&csrs[base + cl * 2]);
  for (int b0 = 0; b0 < pdeg; b0 += 8) {
    uint32_t ent_n = __builtin_nontemporal_load(
        (const uint32_t*)&csrs[base + b0 + 8 + cl * 2]);
    int s0 = (int)(ent & 0xffffu) << 6;
    int s1 = (int)(ent >> 16) << 6;
#pragma unroll
    for (int e = 0; e < 8; ++e) {
      int off = __shfl((e & 1) ? s1 : s0, grp + (e >> 1)) + cb;
      u32x4 v = *(const u32x4*)(Pb + off);
      RACC(v, a0, a1, a2, a3);
    }
    ent = ent_n;
  }
  float di = dinv[i];
  float vv[8];
  vv[0] = di * a0.x + b2[cl * 8 + 0]; vv[1] = di * a0.y + b2[cl * 8 + 1];
  vv[2] = di * a1.x + b2[cl * 8 + 2]; vv[3] = di * a1.y + b2[cl * 8 + 3];
  vv[4] = di * a2.x + b2[cl * 8 + 4]; vv[5] = di * a2.y + b2[cl * 8 + 5];
  vv[6] = di * a3.x + b2[cl * 8 + 6]; vv[7] = di * a3.y + b2[cl * 8 + 7];
  float lp0 = 0.f, lp1 = 0.f;
  const float2* Wl2 = (const float2*)Wl;
#pragma unroll
  for (int k = 0; k < 8; ++k) {
    float2 wl = Wl2[cl * 8 + k];
    lp0 += vv[k] * wl.x;
    lp1 += vv[k] * wl.y;
  }
  lp0 += __shfl_xor(lp0, 1); lp0 += __shfl_xor(lp0, 2);
  lp1 += __shfl_xor(lp1, 1); lp1 += __shfl_xor(lp1, 2);
  if (valid && cl == 0) {
    float l0 = lp0 + bl[0], l1 = lp1 + bl[1];
    float m = fmaxf(l0, l1);
    float lse = m + logf(expf(l0 - m) + expf(l1 - m));
    float2 o; o.x = l0 - lse; o.y = l1 - lse;
    *(float2*)&out[i * 2] = o;
  }
}

extern "C" void kernel_launch(void* const* d_in, const int* in_sizes, int n_in,
                              void* d_out, int out_size, void* d_ws, size_t ws_size,
                              hipStream_t stream) {
  const float* x  = (const float*)d_in[0];
  const int*   ei = (const int*)d_in[1];
  const float* W1 = (const float*)d_in[2];
  const float* b1 = (const float*)d_in[3];
  const float* W2 = (const float*)d_in[4];
  const float* b2 = (const float*)d_in[5];
  const float* Wl = (const float*)d_in[6];
  const float* bl = (const float*)d_in[7];
  float* out = (float*)d_out;

  const int* src = ei;
  const int* dst = ei + NE;

  uint8_t* w = (uint8_t*)d_ws;
  auto alloc = [&](size_t bytes) { void* p = w; w += (bytes + 255) & ~(size_t)255; return p; };
  int*      counts = (int*)alloc((size_t)NCH * NBUCK * 4);
  int*      offs   = (int*)alloc((size_t)NCH * NBUCK * 4);
  int*      bcnt   = (int*)alloc((size_t)NBUCK * 4);
  uint32_t* binned = (uint32_t*)alloc((size_t)NBUCK * CAP * 4);
  uint16_t* csrs   = (uint16_t*)alloc((size_t)NBUCK * CAP2 * 2);
  int*      rowptr2= (int*)alloc((size_t)NN * 4);
  int*      deg2   = (int*)alloc((size_t)NN * 4);
  float*    dinv   = (float*)alloc((size_t)NN * 4);
  bf16_t*   w1t    = (bf16_t*)alloc((size_t)CIN * CH1 * 2);
  bf16_t*   w2t    = (bf16_t*)alloc((size_t)CH1 * CH2 * 2);
  bf16_t*   h1p    = (bf16_t*)alloc((size_t)(NN + 1) * CH1 * 2);  // 8 planes [NN+1][32]
  bf16_t*   h1c    = (bf16_t*)alloc((size_t)(NN + 1) * CH1 * 2);  // contiguous [NN+1][256]
  bf16_t*   hrp    = (bf16_t*)alloc((size_t)NN * CH1 * 2);        // 8 planes [NN][32]
  bf16_t*   h2b    = (bf16_t*)alloc((size_t)(NN + 1) * CH2 * 2);  // row NN = zeros

  k_hist <<<NCH, 256, 0, stream>>>(dst, counts);
  k_scanb<<<NBUCK, 512, 0, stream>>>(counts, offs, bcnt);
  k_bin  <<<NCH, 256, 0, stream>>>(src, dst, offs, binned);
  k_build<<<NBUCK, 256, 0, stream>>>(binned, bcnt, rowptr2, deg2, dinv, csrs);

  k_prep_w<<<(CIN * CH1 + 255) / 256, 256, 0, stream>>>(W1, W2, w1t, w2t,
      (uint32_t*)h1p, (uint32_t*)h2b, (uint32_t*)h1c);

  dim3 g1((NN + BM - 1) / BM);
  k_gemm1<<<g1, 256, 0, stream>>>(x, w1t, dinv, h1p, h1c);

  k_agg1<<<NBP * 8 + NBC, 256, 0, stream>>>((const uint32_t*)h1p,
      (const uint32_t*)h1c, rowptr2, deg2, csrs, dinv, b1, (uint32_t*)hrp);
  k_gemm2<<<(NN / 16 + 3) / 4, 256, 0, stream>>>(hrp, w2t, dinv, h2b);
  int nb = (NN + 63) / 64;
  k_agg2<<<nb, 256, 0, stream>>>((const uint32_t*)h2b, rowptr2, deg2, csrs,
                                 dinv, b2, Wl, bl, out);
}

// Round 13
// 220.588 us; speedup vs baseline: 1.1945x; 1.1945x over previous
//
#include <hip/hip_runtime.h>
#include <hip/hip_bf16.h>
#include <stdint.h>

#define NN 50000
#define NE 1600000
#define CIN 512
#define CH1 256
#define CH2 32

#define NBUCK 196          // ceil(50000/256) buckets of 256 nodes
#define CAP 10240          // per-bucket raw edge capacity (avg 8163, +23 sigma)
#define CAP2 16384         // padded capacity: CAP + 256*16 pad/self <= 14336
#define ECH 4096           // edges per binning block
#define NCH 391            // ceil(NE/ECH)
#define NPREP 512          // prep-work blocks appended to k_hist's grid

typedef __bf16 bf16_t;
typedef __attribute__((ext_vector_type(2))) __bf16 bf16x2;
typedef __attribute__((ext_vector_type(8))) __bf16 bf16x8;
typedef __attribute__((ext_vector_type(4))) float f32x4;
typedef __attribute__((ext_vector_type(2))) float f32x2;
typedef __attribute__((ext_vector_type(4))) uint32_t u32x4;

__device__ inline float blo(uint32_t v) { return __uint_as_float(v << 16); }
__device__ inline float bhi(uint32_t v) { return __uint_as_float(v & 0xffff0000u); }
__device__ inline uint32_t pk2(float a, float b) {
  bf16x2 p; p[0] = (__bf16)a; p[1] = (__bf16)b; return *(uint32_t*)&p;
}
#define RACC(v, A0, A1, A2, A3) { \
    f32x2 t0 = {blo(v.x), bhi(v.x)}; A0 += t0; \
    f32x2 t1 = {blo(v.y), bhi(v.y)}; A1 += t1; \
    f32x2 t2 = {blo(v.z), bhi(v.z)}; A2 += t2; \
    f32x2 t3 = {blo(v.w), bhi(v.w)}; A3 += t3; }

// ============ k_hist + weight-prep fused (independent work, one launch) ============
__global__ __launch_bounds__(256) void k_hist(const int* __restrict__ dst,
    int* __restrict__ counts,
    const float* __restrict__ W1, const float* __restrict__ W2,
    bf16_t* __restrict__ w1t, bf16_t* __restrict__ w2t,
    uint32_t* __restrict__ h1p_u32, uint32_t* __restrict__ h2b_u32) {
  int blk = blockIdx.x, t = threadIdx.x;
  if (blk >= NCH) {
    // ---- prep work ----
    int pb = blk - NCH;
    int i = pb * 256 + t;
    if (i < CIN * CH1) {
      int n = i >> 9, k = i & 511;
      w1t[i] = (__bf16)W1[k * CH1 + n];            // w1t[n][k]
    }
    if (i < CH1 * CH2) {
      int oc = i >> 8, k = i & 255;
      w2t[i] = (__bf16)W2[k * CH2 + oc];           // w2t[oc][k]
    }
    if (pb == 0) {
      if (t < 128) {                                // zero row NN of 8 h1 planes
        int p = t >> 4;
        h1p_u32[((size_t)p * (NN + 1) + NN) * 16 + (t & 15)] = 0;
      } else if (t < 144) {                         // zero row NN of h2b
        h2b_u32[(size_t)NN * 16 + (t - 128)] = 0;
      }
    }
    return;
  }
  // ---- histogram of dst>>8 per edge-chunk ----
  __shared__ int h[256];
  int e0 = blk * ECH;
  int ce = NE - e0; if (ce > ECH) ce = ECH;
  h[t] = 0;
  __syncthreads();
  for (int k = t; k < ce; k += 256) atomicAdd(&h[dst[e0 + k] >> 8], 1);
  __syncthreads();
  if (t < NBUCK) counts[blk * NBUCK + t] = h[t];
}

__global__ __launch_bounds__(512) void k_scanb(const int* __restrict__ counts,
                                               int* __restrict__ offs,
                                               int* __restrict__ bcnt) {
  __shared__ int l[512];
  int b = blockIdx.x, t = threadIdx.x;
  int v = (t < NCH) ? counts[t * NBUCK + b] : 0;
  int x = v;
  l[t] = x;
  __syncthreads();
  for (int off = 1; off < 512; off <<= 1) {
    int u = (t >= off) ? l[t - off] : 0;
    __syncthreads();
    x += u; l[t] = x;
    __syncthreads();
  }
  if (t < NCH) offs[t * NBUCK + b] = b * CAP + (x - v);
  if (t == 511) bcnt[b] = x;
}

// P1c: single-pass direct scatter into block-private regions.
__global__ __launch_bounds__(256) void k_bin(const int* __restrict__ src,
    const int* __restrict__ dst, const int* __restrict__ offs,
    uint32_t* __restrict__ binned) {
  __shared__ int lcnt[256], offsL[256];
  int blk = blockIdx.x, t = threadIdx.x;
  int e0 = blk * ECH;
  int ce = NE - e0; if (ce > ECH) ce = ECH;
  lcnt[t] = 0;
  if (t < NBUCK) offsL[t] = offs[blk * NBUCK + t];
  __syncthreads();
  for (int k = t; k < ce; k += 256) {
    int d = dst[e0 + k], s = src[e0 + k];
    int bkt = d >> 8;
    int p = atomicAdd(&lcnt[bkt], 1);
    binned[offsL[bkt] + p] = ((uint32_t)(d & 255) << 16) | (uint32_t)s;
  }
}

// P2: one block per bucket -> padded u16 src lists with self-loops + sentinels.
// Sentinel src == NN points at the zero row.
__global__ __launch_bounds__(256) void k_build(const uint32_t* __restrict__ binned,
    const int* __restrict__ bcnt, int* __restrict__ rowptr2, int* __restrict__ deg2,
    float* __restrict__ dinv, uint16_t* __restrict__ csrs) {
  __shared__ int hist[256], prow[256], lcnt[256];
  __shared__ int tot_s;
  __shared__ uint32_t c2[CAP2];
  int b = blockIdx.x, t = threadIdx.x;
  int count = bcnt[b];
  hist[t] = 0; lcnt[t] = 0;
  __syncthreads();
  const uint32_t* bb = binned + (size_t)b * CAP;
  for (int j = t; j < count; j += 256) atomicAdd(&hist[bb[j] >> 16], 1);
  __syncthreads();
  int node = b * 256 + t;
  int deg = hist[t];
  int pdeg = (node < NN) ? ((deg + 16) & ~15) : 0;   // deg + self, pad to 16
  int x = pdeg;
  prow[t] = x;
  __syncthreads();
  for (int off = 1; off < 256; off <<= 1) {
    int u = (t >= off) ? prow[t - off] : 0;
    __syncthreads();
    x += u; prow[t] = x;
    __syncthreads();
  }
  int start = x - pdeg;
  prow[t] = start;
  if (t == 255) tot_s = x;
  if (node < NN) {
    rowptr2[node] = b * CAP2 + start;
    deg2[node] = pdeg;
    dinv[node] = 1.0f / sqrtf((float)(deg + 1));     // deg incl. self-loop
    c2[start + deg] = (uint32_t)node;                // self
    for (int k = deg + 1; k < pdeg; ++k)
      c2[start + k] = (uint32_t)NN;                  // pad -> zero row
  }
  __syncthreads();
  for (int j = t; j < count; j += 256) {
    uint32_t e = bb[j];
    int dl = e >> 16;
    int p = prow[dl] + atomicAdd(&lcnt[dl], 1);
    c2[p] = e & 0xffffu;
  }
  __syncthreads();
  int tot = tot_s;
  uint16_t* co = csrs + (size_t)b * CAP2;
  for (int j = t; j < tot; j += 256) co[j] = (uint16_t)c2[j];
}

// ---------------- GEMM1: h1 planes = bf16( dinv .* (x @ W1) ) ----------------
// BM=64 x BN=256: X (the 102 MB input) is read exactly ONCE; W1T (256 KB)
// is L2-resident. h1 layout: 8 planes of [NN+1][32ch] bf16, 3.2 MB per plane.
#define BM 64
#define BN 256
#define BK 64

__global__ __launch_bounds__(256) void k_gemm1(const float* __restrict__ X,
                                               const bf16_t* __restrict__ BT,
                                               const float* __restrict__ dinv,
                                               bf16_t* __restrict__ h1p) {
  __shared__ __align__(16) bf16_t ldsA[2][BM * BK];
  __shared__ __align__(16) bf16_t ldsB[2][BN * BK];
  const int tid = threadIdx.x;
  const int lane = tid & 63;
  const int wid = tid >> 6;          // waves tile the 256-col dim
  const int tm = blockIdx.x;

  f32x4 acc[4][4] = {};
  float4 ra[2], rb[2];

  auto loadA = [&](int kt) {
#pragma unroll
    for (int q = 0; q < 2; ++q) {
      int idx16 = q * 256 + tid;       // 16B-chunk index in 64x64 tile
      int r = idx16 >> 3, cw = idx16 & 7;
      int grow = tm * BM + r;
      grow = grow < NN ? grow : NN - 1;
      const float* ga = X + (size_t)grow * CIN + kt * BK + cw * 8;
      ra[q] = *(const float4*)ga;
      rb[q] = *(const float4*)(ga + 4);
    }
  };
  auto writeA = [&](int buf) {
#pragma unroll
    for (int q = 0; q < 2; ++q) {
      int idx16 = q * 256 + tid;
      int r = idx16 >> 3, cw = idx16 & 7;
      bf16x8 o;
      o[0] = (__bf16)ra[q].x; o[1] = (__bf16)ra[q].y;
      o[2] = (__bf16)ra[q].z; o[3] = (__bf16)ra[q].w;
      o[4] = (__bf16)rb[q].x; o[5] = (__bf16)rb[q].y;
      o[6] = (__bf16)rb[q].z; o[7] = (__bf16)rb[q].w;
      *(bf16x8*)&ldsA[buf][r * 64 + ((cw ^ (r & 7)) << 3)] = o;
    }
  };
  auto stageB = [&](int buf, int kt) {
#pragma unroll
    for (int t = 0; t < 8; ++t) {
      int o = t * 4096 + tid * 16;     // byte offset in 32KB B tile
      int r = o >> 7, cw = (o >> 4) & 7;
      int lc = cw ^ (r & 7);
      const bf16_t* gb = BT + (size_t)r * CIN + kt * BK + lc * 8;
      __builtin_amdgcn_global_load_lds(
          (const __attribute__((address_space(1))) void*)gb,
          (__attribute__((address_space(3))) void*)&ldsB[buf][(t * 4096 + wid * 1024) >> 1],
          16, 0, 0);
    }
  };

  loadA(0);
  stageB(0, 0);
  writeA(0);
  __syncthreads();
  int cur = 0;
  for (int kt = 0; kt < CIN / BK; ++kt) {
    if (kt + 1 < CIN / BK) { loadA(kt + 1); stageB(cur ^ 1, kt + 1); }
#pragma unroll
    for (int ks = 0; ks < 2; ++ks) {
      bf16x8 af[4], bfr[4];
#pragma unroll
      for (int m = 0; m < 4; ++m) {
        int row = m * 16 + (lane & 15);
        int kc = ks * 4 + (lane >> 4);
        af[m] = *(const bf16x8*)&ldsA[cur][row * 64 + ((kc ^ (row & 7)) << 3)];
      }
#pragma unroll
      for (int n = 0; n < 4; ++n) {
        int col = wid * 64 + n * 16 + (lane & 15);
        int kc = ks * 4 + (lane >> 4);
        bfr[n] = *(const bf16x8*)&ldsB[cur][col * 64 + ((kc ^ (col & 7)) << 3)];
      }
#pragma unroll
      for (int m = 0; m < 4; ++m)
#pragma unroll
        for (int n = 0; n < 4; ++n)
          acc[m][n] = __builtin_amdgcn_mfma_f32_16x16x32_bf16(af[m], bfr[n], acc[m][n], 0, 0, 0);
    }
    if (kt + 1 < CIN / BK) writeA(cur ^ 1);
    __syncthreads();
    cur ^= 1;
  }

#pragma unroll
  for (int m = 0; m < 4; ++m) {
#pragma unroll
    for (int r = 0; r < 4; ++r) {
      int grow = tm * BM + m * 16 + (lane >> 4) * 4 + r;
      if (grow < NN) {
        float dv = dinv[grow];
#pragma unroll
        for (int n = 0; n < 4; ++n) {
          int gcol = wid * 64 + n * 16 + (lane & 15);
          int plane = gcol >> 5, pc = gcol & 31;
          h1p[(size_t)plane * ((NN + 1) * 32) + (size_t)grow * 32 + pc] =
              (__bf16)(dv * acc[m][n][r]);
        }
      }
    }
  }
}

// ---------------- agg1: 16 nodes x 4 lanes, dwordx4 row gathers ----------------
// At the measured random-touch wall (~116G 64B line-touches/s chip-wide;
// six structural variants all land at ~110 us). s = blockIdx.x & 7 pins
// each 3.2 MB plane to one XCD's L2.
__global__ __launch_bounds__(256) void k_agg1(const uint32_t* __restrict__ h1p,
    const int* __restrict__ rowptr2, const int* __restrict__ deg2,
    const uint16_t* __restrict__ csrs, const float* __restrict__ dinv,
    const float* __restrict__ bias, uint32_t* __restrict__ hrp) {
  const int s = blockIdx.x & 7;
  const int lane = threadIdx.x & 63;
  const int wid = threadIdx.x >> 6;
  int i = (blockIdx.x >> 3) * 64 + wid * 16 + (lane >> 2);
  const bool valid = i < NN;
  i = valid ? i : NN - 1;
  const int cl = lane & 3;               // owns u32s [4cl,4cl+4) = ch [8cl,8cl+8)
  const int grp = lane & 60;             // group base lane
  const int cb = cl << 4;                // byte offset within 64B row
  const char* __restrict__ Pb = (const char*)(h1p + (size_t)s * ((NN + 1) * 16));

  f32x2 a0 = {0.f, 0.f}, a1 = {0.f, 0.f}, a2 = {0.f, 0.f}, a3 = {0.f, 0.f};
  const int base = rowptr2[i];
  const int pdeg = deg2[i];              // multiple of 16 (so of 8), incl. self+pads
  uint32_t ent = __builtin_nontemporal_load((const uint32_t*)&csrs[base + cl * 2]);
  for (int b0 = 0; b0 < pdeg; b0 += 8) {
    uint32_t ent_n = __builtin_nontemporal_load(
        (const uint32_t*)&csrs[base + b0 + 8 + cl * 2]);   // padded slack: safe
    int s0 = (int)(ent & 0xffffu) << 6;
    int s1 = (int)(ent >> 16) << 6;
    int o0 = __shfl(s0, grp + 0) + cb;
    int o1 = __shfl(s1, grp + 0) + cb;
    int o2 = __shfl(s0, grp + 1) + cb;
    int o3 = __shfl(s1, grp + 1) + cb;
    int o4 = __shfl(s0, grp + 2) + cb;
    int o5 = __shfl(s1, grp + 2) + cb;
    int o6 = __shfl(s0, grp + 3) + cb;
    int o7 = __shfl(s1, grp + 3) + cb;
    u32x4 v0 = *(const u32x4*)(Pb + o0);
    u32x4 v1 = *(const u32x4*)(Pb + o1);
    u32x4 v2 = *(const u32x4*)(Pb + o2);
    u32x4 v3 = *(const u32x4*)(Pb + o3);
    u32x4 v4 = *(const u32x4*)(Pb + o4);
    u32x4 v5 = *(const u32x4*)(Pb + o5);
    u32x4 v6 = *(const u32x4*)(Pb + o6);
    u32x4 v7 = *(const u32x4*)(Pb + o7);
    RACC(v0, a0, a1, a2, a3); RACC(v1, a0, a1, a2, a3);
    RACC(v2, a0, a1, a2, a3); RACC(v3, a0, a1, a2, a3);
    RACC(v4, a0, a1, a2, a3); RACC(v5, a0, a1, a2, a3);
    RACC(v6, a0, a1, a2, a3); RACC(v7, a0, a1, a2, a3);
    ent = ent_n;
  }
  float di = dinv[i];
  float4 b0v = *(const float4*)&bias[s * 32 + cl * 8];
  float4 b1v = *(const float4*)&bias[s * 32 + cl * 8 + 4];
  u32x4 o;
  o.x = pk2(fmaxf(di * a0.x + b0v.x, 0.f), fmaxf(di * a0.y + b0v.y, 0.f));
  o.y = pk2(fmaxf(di * a1.x + b0v.z, 0.f), fmaxf(di * a1.y + b0v.w, 0.f));
  o.z = pk2(fmaxf(di * a2.x + b1v.x, 0.f), fmaxf(di * a2.y + b1v.y, 0.f));
  o.w = pk2(fmaxf(di * a3.x + b1v.z, 0.f), fmaxf(di * a3.y + b1v.w, 0.f));
  if (valid)
    __builtin_nontemporal_store(o,
        (u32x4*)&hrp[((size_t)s * NN + i) * 16 + cl * 4]);
}

// ---------------- GEMM2 (MFMA): h2b = bf16( dinv .* (hr @ W2) ) ----------------
__global__ __launch_bounds__(256) void k_gemm2(const bf16_t* __restrict__ hrp,
    const bf16_t* __restrict__ w2t, const float* __restrict__ dinv,
    bf16_t* __restrict__ h2b) {
  const int lane = threadIdx.x & 63;
  const int gw = blockIdx.x * 4 + (threadIdx.x >> 6);
  const int r0 = gw * 16;
  if (r0 >= NN) return;
  int arow = r0 + (lane & 15);
  arow = arow < NN ? arow : NN - 1;
  const int kc = lane >> 4;
  f32x4 acc0 = {}, acc1 = {};
#pragma unroll
  for (int kb = 0; kb < 8; ++kb) {
    bf16x8 a  = *(const bf16x8*)&hrp[(size_t)kb * (NN * 32) + (size_t)arow * 32 + kc * 8];
    bf16x8 b0 = *(const bf16x8*)&w2t[(size_t)(lane & 15) * CH1 + kb * 32 + kc * 8];
    bf16x8 b1 = *(const bf16x8*)&w2t[(size_t)(16 + (lane & 15)) * CH1 + kb * 32 + kc * 8];
    acc0 = __builtin_amdgcn_mfma_f32_16x16x32_bf16(a, b0, acc0, 0, 0, 0);
    acc1 = __builtin_amdgcn_mfma_f32_16x16x32_bf16(a, b1, acc1, 0, 0, 0);
  }
#pragma unroll
  for (int r = 0; r < 4; ++r) {
    int rr = r0 + (lane >> 4) * 4 + r;
    if (rr < NN) {
      float dv = dinv[rr];
      h2b[(size_t)rr * CH2 + (lane & 15)]      = (__bf16)(dv * acc0[r]);
      h2b[(size_t)rr * CH2 + 16 + (lane & 15)] = (__bf16)(dv * acc1[r]);
    }
  }
}

// ---------------- agg2 + bias + linear + log_softmax (16 nodes x 4 lanes) ----------------
__global__ __launch_bounds__(256) void k_agg2(const uint32_t* __restrict__ h2b,
    const int* __restrict__ rowptr2, const int* __restrict__ deg2,
    const uint16_t* __restrict__ csrs, const float* __restrict__ dinv,
    const float* __restrict__ b2, const float* __restrict__ Wl,
    const float* __restrict__ bl, float* __restrict__ out) {
  const int lane = threadIdx.x & 63;
  const int wid = threadIdx.x >> 6;
  int i = blockIdx.x * 64 + wid * 16 + (lane >> 2);
  const bool valid = i < NN;
  i = valid ? i : NN - 1;
  const int cl = lane & 3;
  const int grp = lane & 60;
  const int cb = cl << 4;
  const char* __restrict__ Pb = (const char*)h2b;

  f32x2 a0 = {0.f, 0.f}, a1 = {0.f, 0.f}, a2 = {0.f, 0.f}, a3 = {0.f, 0.f};
  const int base = rowptr2[i];
  const int pdeg = deg2[i];
  uint32_t ent = __builtin_nontemporal_load((const uint32_t*)&csrs[base + cl * 2]);
  for (int b0 = 0; b0 < pdeg; b0 += 8) {
    uint32_t ent_n = __builtin_nontemporal_load(
        (const uint32_t*)&csrs[base + b0 + 8 + cl * 2]);
    int s0 = (int)(ent & 0xffffu) << 6;
    int s1 = (int)(ent >> 16) << 6;
#pragma unroll
    for (int e = 0; e < 8; ++e) {
      int off = __shfl((e & 1) ? s1 : s0, grp + (e >> 1)) + cb;
      u32x4 v = *(const u32x4*)(Pb + off);
      RACC(v, a0, a1, a2, a3);
    }
    ent = ent_n;
  }
  float di = dinv[i];
  float vv[8];
  vv[0] = di * a0.x + b2[cl * 8 + 0]; vv[1] = di * a0.y + b2[cl * 8 + 1];
  vv[2] = di * a1.x + b2[cl * 8 + 2]; vv[3] = di * a1.y + b2[cl * 8 + 3];
  vv[4] = di * a2.x + b2[cl * 8 + 4]; vv[5] = di * a2.y + b2[cl * 8 + 5];
  vv[6] = di * a3.x + b2[cl * 8 + 6]; vv[7] = di * a3.y + b2[cl * 8 + 7];
  float lp0 = 0.f, lp1 = 0.f;
  const float2* Wl2 = (const float2*)Wl;
#pragma unroll
  for (int k = 0; k < 8; ++k) {
    float2 wl = Wl2[cl * 8 + k];
    lp0 += vv[k] * wl.x;
    lp1 += vv[k] * wl.y;
  }
  lp0 += __shfl_xor(lp0, 1); lp0 += __shfl_xor(lp0, 2);
  lp1 += __shfl_xor(lp1, 1); lp1 += __shfl_xor(lp1, 2);
  if (valid && cl == 0) {
    float l0 = lp0 + bl[0], l1 = lp1 + bl[1];
    float m = fmaxf(l0, l1);
    float lse = m + logf(expf(l0 - m) + expf(l1 - m));
    float2 o; o.x = l0 - lse; o.y = l1 - lse;
    *(float2*)&out[i * 2] = o;
  }
}

extern "C" void kernel_launch(void* const* d_in, const int* in_sizes, int n_in,
                              void* d_out, int out_size, void* d_ws, size_t ws_size,
                              hipStream_t stream) {
  const float* x  = (const float*)d_in[0];
  const int*   ei = (const int*)d_in[1];
  const float* W1 = (const float*)d_in[2];
  const float* b1 = (const float*)d_in[3];
  const float* W2 = (const float*)d_in[4];
  const float* b2 = (const float*)d_in[5];
  const float* Wl = (const float*)d_in[6];
  const float* bl = (const float*)d_in[7];
  float* out = (float*)d_out;

  const int* src = ei;
  const int* dst = ei + NE;

  uint8_t* w = (uint8_t*)d_ws;
  auto alloc = [&](size_t bytes) { void* p = w; w += (bytes + 255) & ~(size_t)255; return p; };
  int*      counts = (int*)alloc((size_t)NCH * NBUCK * 4);
  int*      offs   = (int*)alloc((size_t)NCH * NBUCK * 4);
  int*      bcnt   = (int*)alloc((size_t)NBUCK * 4);
  uint32_t* binned = (uint32_t*)alloc((size_t)NBUCK * CAP * 4);
  uint16_t* csrs   = (uint16_t*)alloc((size_t)NBUCK * CAP2 * 2);
  int*      rowptr2= (int*)alloc((size_t)NN * 4);
  int*      deg2   = (int*)alloc((size_t)NN * 4);
  float*    dinv   = (float*)alloc((size_t)NN * 4);
  bf16_t*   w1t    = (bf16_t*)alloc((size_t)CIN * CH1 * 2);
  bf16_t*   w2t    = (bf16_t*)alloc((size_t)CH1 * CH2 * 2);
  bf16_t*   h1p    = (bf16_t*)alloc((size_t)(NN + 1) * CH1 * 2);  // 8 planes [NN+1][32]
  bf16_t*   hrp    = (bf16_t*)alloc((size_t)NN * CH1 * 2);        // 8 planes [NN][32]
  bf16_t*   h2b    = (bf16_t*)alloc((size_t)(NN + 1) * CH2 * 2);  // row NN = zeros

  k_hist <<<NCH + NPREP, 256, 0, stream>>>(dst, counts, W1, W2, w1t, w2t,
                                           (uint32_t*)h1p, (uint32_t*)h2b);
  k_scanb<<<NBUCK, 512, 0, stream>>>(counts, offs, bcnt);
  k_bin  <<<NCH, 256, 0, stream>>>(src, dst, offs, binned);
  k_build<<<NBUCK, 256, 0, stream>>>(binned, bcnt, rowptr2, deg2, dinv, csrs);

  dim3 g1((NN + BM - 1) / BM);
  k_gemm1<<<g1, 256, 0, stream>>>(x, w1t, dinv, h1p);

  int nb = (NN + 63) / 64;
  k_agg1<<<nb * 8, 256, 0, stream>>>((const uint32_t*)h1p, rowptr2, deg2,
                                     csrs, dinv, b1, (uint32_t*)hrp);
  k_gemm2<<<(NN / 16 + 3) / 4, 256, 0, stream>>>(hrp, w2t, dinv, h2b);
  k_agg2<<<nb, 256, 0, stream>>>((const uint32_t*)h2b, rowptr2, deg2, csrs,
                                 dinv, b2, Wl, bl, out);
}